// Round 1
// baseline (356.976 us; speedup 1.0000x reference)
//
#include <hip/hip_runtime.h>
#include <hip/hip_bf16.h>
#include <stdint.h>
#include <stddef.h>

#define N_PTS 100000
#define KOFF 27

typedef __attribute__((ext_vector_type(8))) __bf16 bf16x8;
typedef __attribute__((ext_vector_type(16))) float f32x16;

__device__ inline unsigned short f2bf(float f) {
  union { float f; unsigned u; } x; x.f = f;
  unsigned r = x.u + 0x7fffu + ((x.u >> 16) & 1u);
  return (unsigned short)(r >> 16);
}

// ---------------- prep: feats->bf16, W1/W2 -> fragment-ordered bf16, zero stats ----------------
__global__ void prep_kernel(const float* __restrict__ feats,
                            const float* __restrict__ W1,
                            const float* __restrict__ W2,
                            unsigned short* __restrict__ featsb,
                            unsigned short* __restrict__ wf1,
                            unsigned short* __restrict__ wf2,
                            float* __restrict__ stats) {
  int tid = blockIdx.x * blockDim.x + threadIdx.x;
  int stride = gridDim.x * blockDim.x;
  const int NF4 = N_PTS * 64 / 4;
  for (int i = tid; i < NF4; i += stride) {
    float4 v = ((const float4*)feats)[i];
    ushort4 o;
    o.x = f2bf(v.x); o.y = f2bf(v.y); o.z = f2bf(v.z); o.w = f2bf(v.w);
    ((ushort4*)featsb)[i] = o;
  }
  // Wf[k][ks][ct][lane][j] = W[k][c = ks*16 + (lane>>5)*8 + j][d = ct*32 + (lane&31)]
  const int WTOT = KOFF * 4096;
  for (int i = tid; i < 2 * WTOT; i += stride) {
    int which = (i >= WTOT) ? 1 : 0;
    int o = which ? (i - WTOT) : i;
    int j = o & 7, l = (o >> 3) & 63, ct = (o >> 9) & 1, ks = (o >> 10) & 3, k = o >> 12;
    int c = ks * 16 + ((l >> 5) << 3) + j;
    int d = (ct << 5) + (l & 31);
    const float* W = which ? W2 : W1;
    float val = W[k * 4096 + c * 64 + d];
    (which ? wf2 : wf1)[o] = f2bf(val);
  }
  for (int i = tid; i < 256; i += stride) stats[i] = 0.f;
}

// ---------------- conv: gathered GEMM via v_mfma_f32_32x32x16_bf16 + fused BN stats ----------------
__global__ __launch_bounds__(256) void conv_kernel(
    const unsigned short* __restrict__ fin,   // [N,64] bf16 bits
    const unsigned short* __restrict__ wf,    // fragment-ordered W, bf16 bits
    const int* __restrict__ idx,              // [K,N]
    const float* __restrict__ mask,           // [K,N] in {0,1}
    float* __restrict__ yout,                 // [N,64] f32 (pre-BN)
    float* __restrict__ gsum,                 // [64]
    float* __restrict__ gsq)                  // [64]
{
  int lane = threadIdx.x & 63;
  int wid  = threadIdx.x >> 6;
  int col  = lane & 31;
  int hi   = lane >> 5;           // 0/1: k-half within fragment
  int n0   = blockIdx.x * 128 + wid * 32;
  int n    = n0 + col;            // this lane's gather row
  bool valid = n < N_PTS;

  f32x16 acc0, acc1;
#pragma unroll
  for (int r = 0; r < 16; ++r) { acc0[r] = 0.f; acc1[r] = 0.f; }

  const uint4* wfv = (const uint4*)wf;

  for (int k = 0; k < KOFF; ++k) {
    int gi = 0; float m = 0.f;
    if (valid) {
      gi = idx[k * N_PTS + n];
      m  = mask[k * N_PTS + n];
    }
    const uint4* arow = (const uint4*)(fin + (size_t)gi * 64);
    uint4 a0 = arow[hi];
    uint4 a1 = arow[2 + hi];
    uint4 a2 = arow[4 + hi];
    uint4 a3 = arow[6 + hi];
    if (m == 0.f) {
      a0 = make_uint4(0u, 0u, 0u, 0u); a1 = a0; a2 = a0; a3 = a0;
    }
    const uint4* bp = wfv + (size_t)k * 512 + lane;
    uint4 b00 = bp[0];   uint4 b01 = bp[64];
    uint4 b10 = bp[128]; uint4 b11 = bp[192];
    uint4 b20 = bp[256]; uint4 b21 = bp[320];
    uint4 b30 = bp[384]; uint4 b31 = bp[448];

    acc0 = __builtin_amdgcn_mfma_f32_32x32x16_bf16(__builtin_bit_cast(bf16x8, a0), __builtin_bit_cast(bf16x8, b00), acc0, 0, 0, 0);
    acc1 = __builtin_amdgcn_mfma_f32_32x32x16_bf16(__builtin_bit_cast(bf16x8, a0), __builtin_bit_cast(bf16x8, b01), acc1, 0, 0, 0);
    acc0 = __builtin_amdgcn_mfma_f32_32x32x16_bf16(__builtin_bit_cast(bf16x8, a1), __builtin_bit_cast(bf16x8, b10), acc0, 0, 0, 0);
    acc1 = __builtin_amdgcn_mfma_f32_32x32x16_bf16(__builtin_bit_cast(bf16x8, a1), __builtin_bit_cast(bf16x8, b11), acc1, 0, 0, 0);
    acc0 = __builtin_amdgcn_mfma_f32_32x32x16_bf16(__builtin_bit_cast(bf16x8, a2), __builtin_bit_cast(bf16x8, b20), acc0, 0, 0, 0);
    acc1 = __builtin_amdgcn_mfma_f32_32x32x16_bf16(__builtin_bit_cast(bf16x8, a2), __builtin_bit_cast(bf16x8, b21), acc1, 0, 0, 0);
    acc0 = __builtin_amdgcn_mfma_f32_32x32x16_bf16(__builtin_bit_cast(bf16x8, a3), __builtin_bit_cast(bf16x8, b30), acc0, 0, 0, 0);
    acc1 = __builtin_amdgcn_mfma_f32_32x32x16_bf16(__builtin_bit_cast(bf16x8, a3), __builtin_bit_cast(bf16x8, b31), acc1, 0, 0, 0);
  }

  // C/D layout (m74/m101): col = lane&31, row = (r&3) + 8*(r>>2) + 4*(lane>>5)
  __shared__ float s_sum[64], s_sq[64];
  if (threadIdx.x < 64) { s_sum[threadIdx.x] = 0.f; s_sq[threadIdx.x] = 0.f; }
  __syncthreads();

  float s0 = 0.f, q0 = 0.f, s1 = 0.f, q1 = 0.f;
#pragma unroll
  for (int r = 0; r < 16; ++r) {
    float v = acc0[r]; s0 += v; q0 += v * v;
    float w = acc1[r]; s1 += w; q1 += w * w;
    int rr = (r & 3) + ((r >> 2) << 3) + (hi << 2);
    int nr = n0 + rr;
    if (nr < N_PTS) {
      yout[(size_t)nr * 64 + col]      = v;
      yout[(size_t)nr * 64 + 32 + col] = w;
    }
  }
  atomicAdd(&s_sum[col], s0);
  atomicAdd(&s_sq[col],  q0);
  atomicAdd(&s_sum[32 + col], s1);
  atomicAdd(&s_sq[32 + col],  q1);
  __syncthreads();
  if (threadIdx.x < 64) {
    atomicAdd(&gsum[threadIdx.x], s_sum[threadIdx.x]);
    atomicAdd(&gsq[threadIdx.x],  s_sq[threadIdx.x]);
  }
}

// ---------------- BN1 + ReLU -> bf16 ----------------
__global__ void bn1_kernel(const float* __restrict__ y,
                           const float* __restrict__ sum,
                           const float* __restrict__ sq,
                           const float* __restrict__ gamma,
                           const float* __restrict__ beta,
                           unsigned short* __restrict__ outb) {
  __shared__ float s_scale[64], s_shift[64];
  if (threadIdx.x < 64) {
    int c = threadIdx.x;
    float mean = sum[c] * (1.f / N_PTS);
    float var  = sq[c] * (1.f / N_PTS) - mean * mean;
    float inv  = rsqrtf(var + 1e-5f);
    float sc   = gamma[c] * inv;
    s_scale[c] = sc;
    s_shift[c] = beta[c] - mean * sc;
  }
  __syncthreads();
  int tid = blockIdx.x * blockDim.x + threadIdx.x;
  int stride = gridDim.x * blockDim.x;
  const int NT = N_PTS * 64 / 4;
  for (int i = tid; i < NT; i += stride) {
    float4 v = ((const float4*)y)[i];
    int c = (i * 4) & 63;
    float r0 = fmaxf(v.x * s_scale[c]     + s_shift[c],     0.f);
    float r1 = fmaxf(v.y * s_scale[c + 1] + s_shift[c + 1], 0.f);
    float r2 = fmaxf(v.z * s_scale[c + 2] + s_shift[c + 2], 0.f);
    float r3 = fmaxf(v.w * s_scale[c + 3] + s_shift[c + 3], 0.f);
    ushort4 o;
    o.x = f2bf(r0); o.y = f2bf(r1); o.z = f2bf(r2); o.w = f2bf(r3);
    ((ushort4*)outb)[i] = o;
  }
}

// ---------------- BN2 + residual + ReLU -> f32 ----------------
__global__ void bn2_kernel(const float* __restrict__ y,
                           const float* __restrict__ sum,
                           const float* __restrict__ sq,
                           const float* __restrict__ gamma,
                           const float* __restrict__ beta,
                           const float* __restrict__ feats,
                           float* __restrict__ out) {
  __shared__ float s_scale[64], s_shift[64];
  if (threadIdx.x < 64) {
    int c = threadIdx.x;
    float mean = sum[c] * (1.f / N_PTS);
    float var  = sq[c] * (1.f / N_PTS) - mean * mean;
    float inv  = rsqrtf(var + 1e-5f);
    float sc   = gamma[c] * inv;
    s_scale[c] = sc;
    s_shift[c] = beta[c] - mean * sc;
  }
  __syncthreads();
  int tid = blockIdx.x * blockDim.x + threadIdx.x;
  int stride = gridDim.x * blockDim.x;
  const int NT = N_PTS * 64 / 4;
  for (int i = tid; i < NT; i += stride) {
    float4 v = ((const float4*)y)[i];
    float4 f = ((const float4*)feats)[i];
    int c = (i * 4) & 63;
    float4 o;
    o.x = fmaxf(v.x * s_scale[c]     + s_shift[c]     + f.x, 0.f);
    o.y = fmaxf(v.y * s_scale[c + 1] + s_shift[c + 1] + f.y, 0.f);
    o.z = fmaxf(v.z * s_scale[c + 2] + s_shift[c + 2] + f.z, 0.f);
    o.w = fmaxf(v.w * s_scale[c + 3] + s_shift[c + 3] + f.w, 0.f);
    ((float4*)out)[i] = o;
  }
}

// ---------------- launch ----------------
extern "C" void kernel_launch(void* const* d_in, const int* in_sizes, int n_in,
                              void* d_out, int out_size, void* d_ws, size_t ws_size,
                              hipStream_t stream) {
  const float* feats  = (const float*)d_in[0];
  const float* W1     = (const float*)d_in[1];
  const float* gamma1 = (const float*)d_in[2];
  const float* beta1  = (const float*)d_in[3];
  const float* W2     = (const float*)d_in[4];
  const float* gamma2 = (const float*)d_in[5];
  const float* beta2  = (const float*)d_in[6];
  const int*   idx1   = (const int*)d_in[7];
  const float* mask1  = (const float*)d_in[8];
  const int*   idx2   = (const int*)d_in[9];
  const float* mask2  = (const float*)d_in[10];
  float* out = (float*)d_out;

  char* ws = (char*)d_ws;
  unsigned short* featsb = (unsigned short*)(ws + 0);          // 12,800,000 B
  unsigned short* wf1    = (unsigned short*)(ws + 12800000);   //    221,184 B
  unsigned short* wf2    = (unsigned short*)(ws + 13021184);   //    221,184 B
  float*          stats  = (float*)(ws + 13242368);            //      1,024 B
  unsigned short* f2b    = (unsigned short*)(ws + 13243392);   // 12,800,000 B

  float* sum1 = stats;       float* sq1 = stats + 64;
  float* sum2 = stats + 128; float* sq2 = stats + 192;

  // y1 and y2 both live in d_out (f32 [N,64]); each is fully dead before overwritten.
  float* y = out;

  prep_kernel<<<1024, 256, 0, stream>>>(feats, W1, W2, featsb, wf1, wf2, stats);

  const int CONV_GRID = (N_PTS + 127) / 128;  // 782
  conv_kernel<<<CONV_GRID, 256, 0, stream>>>(featsb, wf1, idx1, mask1, y, sum1, sq1);
  bn1_kernel<<<1024, 256, 0, stream>>>(y, sum1, sq1, gamma1, beta1, f2b);
  conv_kernel<<<CONV_GRID, 256, 0, stream>>>(f2b, wf2, idx2, mask2, y, sum2, sq2);
  bn2_kernel<<<1024, 256, 0, stream>>>(y, sum2, sq2, gamma2, beta2, feats, out);
}

// Round 2
// 335.080 us; speedup vs baseline: 1.0653x; 1.0653x over previous
//
#include <hip/hip_runtime.h>
#include <hip/hip_bf16.h>
#include <stdint.h>
#include <stddef.h>

#define N_PTS 100000
#define KOFF 27

typedef __attribute__((ext_vector_type(8))) __bf16 bf16x8;
typedef __attribute__((ext_vector_type(16))) float f32x16;

__device__ inline unsigned short f2bf(float f) {
  union { float f; unsigned u; } x; x.f = f;
  unsigned r = x.u + 0x7fffu + ((x.u >> 16) & 1u);
  return (unsigned short)(r >> 16);
}

// ---------------- fprep: feats->bf16, zero stats, zero rows N of featsb/f2b ----------------
__global__ void fprep_kernel(const float* __restrict__ feats,
                             unsigned short* __restrict__ featsb,
                             unsigned short* __restrict__ f2b,
                             float* __restrict__ stats) {
  int tid = blockIdx.x * blockDim.x + threadIdx.x;
  int stride = gridDim.x * blockDim.x;
  const int NF4 = N_PTS * 16;
  for (int i = tid; i < NF4; i += stride) {
    float4 v = ((const float4*)feats)[i];
    ushort4 o;
    o.x = f2bf(v.x); o.y = f2bf(v.y); o.z = f2bf(v.z); o.w = f2bf(v.w);
    ((ushort4*)featsb)[i] = o;
  }
  if (tid < 256) stats[tid] = 0.f;
  if (tid >= 256 && tid < 264) {
    uint4 z = make_uint4(0u, 0u, 0u, 0u);
    ((uint4*)(featsb + (size_t)N_PTS * 64))[tid - 256] = z;
  }
  if (tid >= 264 && tid < 272) {
    uint4 z = make_uint4(0u, 0u, 0u, 0u);
    ((uint4*)(f2b + (size_t)N_PTS * 64))[tid - 264] = z;
  }
}

// ---------------- wprep: W -> fragment-ordered bf16 via LDS staging ----------------
// Wf[k][ks][ct][lane][j] = W[k][c = ks*16 + (lane>>5)*8 + j][d = ct*32 + (lane&31)]
__global__ __launch_bounds__(256) void wprep_kernel(const float* __restrict__ W1,
                                                    const float* __restrict__ W2,
                                                    unsigned short* __restrict__ wf1,
                                                    unsigned short* __restrict__ wf2) {
  __shared__ float sW[4096];
  int which = blockIdx.x & 1;
  int k = blockIdx.x >> 1;
  const float* W = (which ? W2 : W1) + (size_t)k * 4096;
  unsigned short* wf = (which ? wf2 : wf1) + (size_t)k * 4096;
  int t = threadIdx.x;
#pragma unroll
  for (int i = 0; i < 4; ++i) {
    ((float4*)sW)[t + 256 * i] = ((const float4*)W)[t + 256 * i];
  }
  __syncthreads();
#pragma unroll
  for (int i = 0; i < 16; ++i) {
    int o = i * 256 + t;
    int j = o & 7, l = (o >> 3) & 63, ct = (o >> 9) & 1, ks = o >> 10;
    int c = ks * 16 + ((l >> 5) << 3) + j;
    int d = (ct << 5) + (l & 31);
    wf[o] = f2bf(sW[c * 64 + d]);
  }
}

// ---------------- conv: gathered GEMM, software-pipelined, fused BN stats ----------------
#define MFMA(a, b, c) __builtin_amdgcn_mfma_f32_32x32x16_bf16(__builtin_bit_cast(bf16x8, a), __builtin_bit_cast(bf16x8, b), c, 0, 0, 0)

// STEP: consume (Ac,Bc) = tile k with 8 MFMAs; gather tile k+1 into (An,Bn) using
// (giN,mN); prefetch idx/mask for k+2 into (giF,mF).
#define STEP(Ac, Bc, An, Bn, giN, mN, giF, mF, kcur)                         \
  {                                                                          \
    int gie = (mN != 0.f) ? giN : N_PTS;                                     \
    const uint4* ar = (const uint4*)(fin + (size_t)gie * 64);                \
    An[0] = ar[hi]; An[1] = ar[2 + hi]; An[2] = ar[4 + hi]; An[3] = ar[6 + hi]; \
    {                                                                        \
      int kn = ((kcur) + 1 <= 26) ? (kcur) + 1 : 26;                         \
      const uint4* bp = wfv + (size_t)kn * 512 + lane;                       \
      Bn[0] = bp[0];   Bn[1] = bp[64];  Bn[2] = bp[128]; Bn[3] = bp[192];    \
      Bn[4] = bp[256]; Bn[5] = bp[320]; Bn[6] = bp[384]; Bn[7] = bp[448];    \
    }                                                                        \
    {                                                                        \
      int kf = ((kcur) + 2 <= 26) ? (kcur) + 2 : 26;                         \
      giF = idxp[kf * N_PTS];                                                \
      float mt = mp[kf * N_PTS];                                             \
      mF = valid ? mt : 0.f;                                                 \
    }                                                                        \
    acc0 = MFMA(Ac[0], Bc[0], acc0);                                         \
    acc1 = MFMA(Ac[0], Bc[1], acc1);                                         \
    acc0 = MFMA(Ac[1], Bc[2], acc0);                                         \
    acc1 = MFMA(Ac[1], Bc[3], acc1);                                         \
    acc0 = MFMA(Ac[2], Bc[4], acc0);                                         \
    acc1 = MFMA(Ac[2], Bc[5], acc1);                                         \
    acc0 = MFMA(Ac[3], Bc[6], acc0);                                         \
    acc1 = MFMA(Ac[3], Bc[7], acc1);                                         \
  }

__global__ __launch_bounds__(256, 3) void conv_kernel(
    const unsigned short* __restrict__ fin,   // [N+1,64] bf16 bits; row N_PTS = zeros
    const unsigned short* __restrict__ wf,    // fragment-ordered W, bf16 bits
    const int* __restrict__ idx,              // [K,N]
    const float* __restrict__ mask,           // [K,N] in {0,1}
    float* __restrict__ yout,                 // [N,64] f32 (pre-BN)
    float* __restrict__ gsum,                 // [64]
    float* __restrict__ gsq)                  // [64]
{
  int lane = threadIdx.x & 63;
  int wid  = threadIdx.x >> 6;
  int col  = lane & 31;
  int hi   = lane >> 5;
  int n0   = blockIdx.x * 128 + wid * 32;
  int n    = n0 + col;
  bool valid = n < N_PTS;
  int nc = valid ? n : (N_PTS - 1);

  const int*   idxp = idx + nc;
  const float* mp   = mask + nc;
  const uint4* wfv  = (const uint4*)wf;

  f32x16 acc0, acc1;
#pragma unroll
  for (int r = 0; r < 16; ++r) { acc0[r] = 0.f; acc1[r] = 0.f; }

  uint4 A0[4], A1[4], B0[8], B1[8];
  int gi0, gi1; float m0, m1;

  // prologue: tile 0 into buf0; idx/mask for k=1 into (gi1,m1)
  gi0 = idxp[0];
  { float mt = mp[0]; m0 = valid ? mt : 0.f; }
  {
    int gie = (m0 != 0.f) ? gi0 : N_PTS;
    const uint4* ar = (const uint4*)(fin + (size_t)gie * 64);
    A0[0] = ar[hi]; A0[1] = ar[2 + hi]; A0[2] = ar[4 + hi]; A0[3] = ar[6 + hi];
    const uint4* bp = wfv + lane;
    B0[0] = bp[0];   B0[1] = bp[64];  B0[2] = bp[128]; B0[3] = bp[192];
    B0[4] = bp[256]; B0[5] = bp[320]; B0[6] = bp[384]; B0[7] = bp[448];
  }
  gi1 = idxp[N_PTS];
  { float mt = mp[N_PTS]; m1 = valid ? mt : 0.f; }

  for (int kk = 0; kk < 13; ++kk) {
    int k = 2 * kk;
    STEP(A0, B0, A1, B1, gi1, m1, gi0, m0, k);
    STEP(A1, B1, A0, B0, gi0, m0, gi1, m1, k + 1);
  }
  // epilogue: tile k=26 in buf0
  acc0 = MFMA(A0[0], B0[0], acc0);
  acc1 = MFMA(A0[0], B0[1], acc1);
  acc0 = MFMA(A0[1], B0[2], acc0);
  acc1 = MFMA(A0[1], B0[3], acc1);
  acc0 = MFMA(A0[2], B0[4], acc0);
  acc1 = MFMA(A0[2], B0[5], acc1);
  acc0 = MFMA(A0[3], B0[6], acc0);
  acc1 = MFMA(A0[3], B0[7], acc1);

  // C/D layout: col = lane&31, row = (r&3) + 8*(r>>2) + 4*(lane>>5)
  __shared__ float s_sum[64], s_sq[64];
  if (threadIdx.x < 64) { s_sum[threadIdx.x] = 0.f; s_sq[threadIdx.x] = 0.f; }
  __syncthreads();

  float s0 = 0.f, q0 = 0.f, s1 = 0.f, q1 = 0.f;
#pragma unroll
  for (int r = 0; r < 16; ++r) {
    float v = acc0[r]; s0 += v; q0 += v * v;
    float w = acc1[r]; s1 += w; q1 += w * w;
    int rr = (r & 3) + ((r >> 2) << 3) + (hi << 2);
    int nr = n0 + rr;
    if (nr < N_PTS) {
      yout[(size_t)nr * 64 + col]      = v;
      yout[(size_t)nr * 64 + 32 + col] = w;
    }
  }
  atomicAdd(&s_sum[col], s0);
  atomicAdd(&s_sq[col],  q0);
  atomicAdd(&s_sum[32 + col], s1);
  atomicAdd(&s_sq[32 + col],  q1);
  __syncthreads();
  if (threadIdx.x < 64) {
    atomicAdd(&gsum[threadIdx.x], s_sum[threadIdx.x]);
    atomicAdd(&gsq[threadIdx.x],  s_sq[threadIdx.x]);
  }
}

// ---------------- BN1 + ReLU -> bf16 ----------------
__global__ void bn1_kernel(const float* __restrict__ y,
                           const float* __restrict__ sum,
                           const float* __restrict__ sq,
                           const float* __restrict__ gamma,
                           const float* __restrict__ beta,
                           unsigned short* __restrict__ outb) {
  __shared__ float s_scale[64], s_shift[64];
  if (threadIdx.x < 64) {
    int c = threadIdx.x;
    float mean = sum[c] * (1.f / N_PTS);
    float var  = sq[c] * (1.f / N_PTS) - mean * mean;
    float inv  = rsqrtf(var + 1e-5f);
    float sc   = gamma[c] * inv;
    s_scale[c] = sc;
    s_shift[c] = beta[c] - mean * sc;
  }
  __syncthreads();
  int tid = blockIdx.x * blockDim.x + threadIdx.x;
  int stride = gridDim.x * blockDim.x;
  const int NT = N_PTS * 16;
  for (int i = tid; i < NT; i += stride) {
    float4 v = ((const float4*)y)[i];
    int c = (i * 4) & 63;
    float r0 = fmaxf(v.x * s_scale[c]     + s_shift[c],     0.f);
    float r1 = fmaxf(v.y * s_scale[c + 1] + s_shift[c + 1], 0.f);
    float r2 = fmaxf(v.z * s_scale[c + 2] + s_shift[c + 2], 0.f);
    float r3 = fmaxf(v.w * s_scale[c + 3] + s_shift[c + 3], 0.f);
    ushort4 o;
    o.x = f2bf(r0); o.y = f2bf(r1); o.z = f2bf(r2); o.w = f2bf(r3);
    ((ushort4*)outb)[i] = o;
  }
}

// ---------------- BN2 + residual + ReLU -> f32 ----------------
__global__ void bn2_kernel(const float* __restrict__ y,
                           const float* __restrict__ sum,
                           const float* __restrict__ sq,
                           const float* __restrict__ gamma,
                           const float* __restrict__ beta,
                           const float* __restrict__ feats,
                           float* __restrict__ out) {
  __shared__ float s_scale[64], s_shift[64];
  if (threadIdx.x < 64) {
    int c = threadIdx.x;
    float mean = sum[c] * (1.f / N_PTS);
    float var  = sq[c] * (1.f / N_PTS) - mean * mean;
    float inv  = rsqrtf(var + 1e-5f);
    float sc   = gamma[c] * inv;
    s_scale[c] = sc;
    s_shift[c] = beta[c] - mean * sc;
  }
  __syncthreads();
  int tid = blockIdx.x * blockDim.x + threadIdx.x;
  int stride = gridDim.x * blockDim.x;
  const int NT = N_PTS * 16;
  for (int i = tid; i < NT; i += stride) {
    float4 v = ((const float4*)y)[i];
    float4 f = ((const float4*)feats)[i];
    int c = (i * 4) & 63;
    float4 o;
    o.x = fmaxf(v.x * s_scale[c]     + s_shift[c]     + f.x, 0.f);
    o.y = fmaxf(v.y * s_scale[c + 1] + s_shift[c + 1] + f.y, 0.f);
    o.z = fmaxf(v.z * s_scale[c + 2] + s_shift[c + 2] + f.z, 0.f);
    o.w = fmaxf(v.w * s_scale[c + 3] + s_shift[c + 3] + f.w, 0.f);
    ((float4*)out)[i] = o;
  }
}

// ---------------- launch ----------------
extern "C" void kernel_launch(void* const* d_in, const int* in_sizes, int n_in,
                              void* d_out, int out_size, void* d_ws, size_t ws_size,
                              hipStream_t stream) {
  const float* feats  = (const float*)d_in[0];
  const float* W1     = (const float*)d_in[1];
  const float* gamma1 = (const float*)d_in[2];
  const float* beta1  = (const float*)d_in[3];
  const float* W2     = (const float*)d_in[4];
  const float* gamma2 = (const float*)d_in[5];
  const float* beta2  = (const float*)d_in[6];
  const int*   idx1   = (const int*)d_in[7];
  const float* mask1  = (const float*)d_in[8];
  const int*   idx2   = (const int*)d_in[9];
  const float* mask2  = (const float*)d_in[10];
  float* out = (float*)d_out;

  char* ws = (char*)d_ws;
  unsigned short* featsb = (unsigned short*)(ws + 0);          // (N+1)*128 = 12,800,128 B
  unsigned short* wf1    = (unsigned short*)(ws + 12800768);   //    221,184 B
  unsigned short* wf2    = (unsigned short*)(ws + 13021952);   //    221,184 B
  float*          stats  = (float*)(ws + 13243136);            //      1,024 B
  unsigned short* f2b    = (unsigned short*)(ws + 13244160);   // 12,800,128 B

  float* sum1 = stats;       float* sq1 = stats + 64;
  float* sum2 = stats + 128; float* sq2 = stats + 192;

  float* y = out;  // f32 [N,64] staging; dead before each overwrite

  fprep_kernel<<<1024, 256, 0, stream>>>(feats, featsb, f2b, stats);
  wprep_kernel<<<54, 256, 0, stream>>>(W1, W2, wf1, wf2);

  const int CONV_GRID = (N_PTS + 127) / 128;  // 782
  conv_kernel<<<CONV_GRID, 256, 0, stream>>>(featsb, wf1, idx1, mask1, y, sum1, sq1);
  bn1_kernel<<<1024, 256, 0, stream>>>(y, sum1, sq1, gamma1, beta1, f2b);
  conv_kernel<<<CONV_GRID, 256, 0, stream>>>(f2b, wf2, idx2, mask2, y, sum2, sq2);
  bn2_kernel<<<1024, 256, 0, stream>>>(y, sum2, sq2, gamma2, beta2, feats, out);
}